// Round 4
// baseline (3082.527 us; speedup 1.0000x reference)
//
#include <hip/hip_runtime.h>
#include <hip/hip_fp16.h>

// GCN layer: out = leaky_relu( segment_sum(edge_vals[:,None] * embeds[col], row, N), 0.5 )
// E = 3.2M, N = 100000, D = 128, f32 in/out.
//
// R6: replace linked-list chase (latency-bound reduce) + far-atomicExch build
//     (memory-side atomic cap, ~165us) with atomic-free radix binning:
//       1. hist:    per-block LDS histogram of bins (row>>7), + fused f32->f16
//                   embeds conversion in trailing blocks. No global atomics.
//       2. scan:    one-block exclusive scan of hist[nbins][NBLK] (200K u32).
//       3. scatter: re-read chunk, write 8B entries {key,val} at deterministic
//                   per-(block,bin) offsets (LDS cursors). No global atomics.
//       4. reduce:  one block per bin; waves stream contiguous entries with
//                   8-deep unroll (full MLP, no dependent chase); accumulate
//                   into a 64KB LDS tile (ds_add_f32); fused leaky_relu +
//                   coalesced f32x4 stores. Bins own disjoint row ranges.

#define GCN_D       128
#define LEAKY_SLOPE 0.5f
#define NBLK        256      // hist/scatter blocks (chunk partition of E)
#define RPB         128      // rows per bin
#define NBINS_MAX   1024
#define NCHAIN_FB   4

typedef float f32x4 __attribute__((ext_vector_type(4)));
typedef unsigned int u32x4 __attribute__((ext_vector_type(4)));

__device__ inline unsigned pack_half2(float a, float b) {
    __half2 h = __floats2half2_rn(a, b);
    return *reinterpret_cast<unsigned*>(&h);
}

// ---------------- Pass 1: histogram + fused f32->f16 conversion ----------------

__global__ void hist_convert_kernel(const int* __restrict__ row,
                                    int E, int CH, int nbins,
                                    unsigned* __restrict__ hist,   // [nbins][NBLK]
                                    const f32x4* __restrict__ emb4,
                                    int n8,
                                    u32x4* __restrict__ h8) {
    __shared__ unsigned h[NBINS_MAX];
    if ((int)blockIdx.x < NBLK) {
        int b = blockIdx.x;
        for (int i = threadIdx.x; i < nbins; i += blockDim.x) h[i] = 0u;
        __syncthreads();
        int s = b * CH;
        int e = min(E, s + CH);
        for (int i = s + threadIdx.x; i < e; i += blockDim.x)
            atomicAdd(&h[row[i] >> 7], 1u);
        __syncthreads();
        for (int i = threadIdx.x; i < nbins; i += blockDim.x)
            hist[(long long)i * NBLK + b] = h[i];
    } else {
        int bid = (int)blockIdx.x - NBLK;
        int nb  = (int)gridDim.x - NBLK;
        int stride = nb * blockDim.x;
        for (int i = bid * blockDim.x + threadIdx.x; i < n8; i += stride) {
            f32x4 a = __builtin_nontemporal_load(&emb4[2 * i]);
            f32x4 b2 = __builtin_nontemporal_load(&emb4[2 * i + 1]);
            u32x4 o;
            o.x = pack_half2(a.x, a.y);
            o.y = pack_half2(a.z, a.w);
            o.z = pack_half2(b2.x, b2.y);
            o.w = pack_half2(b2.z, b2.w);
            __builtin_nontemporal_store(o, &h8[i]);
        }
    }
}

// ---------------- Pass 2: one-block exclusive scan over M = nbins*NBLK ----------------

__global__ void __launch_bounds__(1024)
scan_kernel(unsigned* __restrict__ data, int M) {
    __shared__ unsigned part[1024];
    int t = threadIdx.x;
    int chunk = (M + 1023) >> 10;
    long long base = (long long)t * chunk;

    unsigned s = 0;
    for (int i = 0; i < chunk; ++i) {
        long long j = base + i;
        if (j < M) s += data[j];
    }
    part[t] = s;
    __syncthreads();

    // Hillis-Steele inclusive scan in LDS.
    for (int off = 1; off < 1024; off <<= 1) {
        unsigned v = (t >= off) ? part[t - off] : 0u;
        __syncthreads();
        part[t] += v;
        __syncthreads();
    }
    unsigned run = (t == 0) ? 0u : part[t - 1];

    for (int i = 0; i < chunk; ++i) {
        long long j = base + i;
        if (j < M) {
            unsigned v = data[j];
            data[j] = run;
            run += v;
        }
    }
}

// ---------------- Pass 3: scatter entries at deterministic offsets ----------------

__global__ void scatter_kernel(const int* __restrict__ row,
                               const int* __restrict__ col,
                               const float* __restrict__ val,
                               int E, int CH, int nbins,
                               const unsigned* __restrict__ scanned, // [nbins][NBLK]
                               uint2* __restrict__ entry) {
    __shared__ unsigned cur[NBINS_MAX];
    int b = blockIdx.x;
    for (int i = threadIdx.x; i < nbins; i += blockDim.x)
        cur[i] = scanned[(long long)i * NBLK + b];
    __syncthreads();

    int s = b * CH;
    int e = min(E, s + CH);
    for (int i = s + threadIdx.x; i < e; i += blockDim.x) {
        int r = row[i];
        unsigned key = ((unsigned)(r & (RPB - 1)) << 17) | (unsigned)col[i];
        unsigned pos = atomicAdd(&cur[r >> 7], 1u);
        entry[pos] = make_uint2(key, __float_as_uint(val[i]));
    }
}

// ---------------- Pass 4: per-bin LDS-tile reduce ----------------

__global__ void __launch_bounds__(512)
bin_reduce_kernel(const unsigned* __restrict__ scanned,
                  const uint2* __restrict__ entry,
                  const __half2* __restrict__ ebh,   // N*64 half2
                  float* __restrict__ out,
                  int E, int N, int nbins) {
    __shared__ float tile[RPB * GCN_D];   // 64 KB
    int b   = blockIdx.x;
    int tid = threadIdx.x;

    for (int i = tid; i < RPB * GCN_D; i += 512) tile[i] = 0.f;

    int seg0 = (int)scanned[(long long)b * NBLK];
    int seg1 = (b + 1 < nbins) ? (int)scanned[(long long)(b + 1) * NBLK] : E;
    __syncthreads();

    int wave = tid >> 6;      // 0..7
    int lane = tid & 63;
    int cpair = 2 * lane;     // this lane's column pair

    int e = seg0 + wave;

    // 8-deep unrolled stream: 8 independent entry loads -> 8 independent
    // coalesced 256B gathers -> 16 ds_add_f32.  No dependent chase.
    while (e + 56 < seg1) {
        uint2 q[8];
        #pragma unroll
        for (int k = 0; k < 8; ++k) q[k] = entry[e + 8 * k];

        __half2 m[8];
        #pragma unroll
        for (int k = 0; k < 8; ++k)
            m[k] = ebh[(long long)(q[k].x & 0x1FFFFu) * 64 + lane];

        #pragma unroll
        for (int k = 0; k < 8; ++k) {
            int    rl = (int)(q[k].x >> 17);
            float  v  = __uint_as_float(q[k].y);
            float2 f  = __half22float2(m[k]);
            atomicAdd(&tile[rl * GCN_D + cpair],     v * f.x);
            atomicAdd(&tile[rl * GCN_D + cpair + 1], v * f.y);
        }
        e += 64;
    }
    for (; e < seg1; e += 8) {
        uint2  q = entry[e];
        __half2 mm = ebh[(long long)(q.x & 0x1FFFFu) * 64 + lane];
        int    rl = (int)(q.x >> 17);
        float  v  = __uint_as_float(q.y);
        float2 f  = __half22float2(mm);
        atomicAdd(&tile[rl * GCN_D + cpair],     v * f.x);
        atomicAdd(&tile[rl * GCN_D + cpair + 1], v * f.y);
    }

    __syncthreads();

    // Fused leaky_relu + coalesced f32x4 stores; bin owns rows exclusively.
    int gbase = b * RPB;
    for (int i = tid; i < RPB * (GCN_D / 4); i += 512) {
        int r  = i >> 5;          // row in tile
        int cq = i & 31;          // f32x4 group in row
        int gr = gbase + r;
        if (gr >= N) continue;
        f32x4 x = *reinterpret_cast<const f32x4*>(&tile[r * GCN_D + cq * 4]);
        x.x = x.x > 0.f ? x.x : LEAKY_SLOPE * x.x;
        x.y = x.y > 0.f ? x.y : LEAKY_SLOPE * x.y;
        x.z = x.z > 0.f ? x.z : LEAKY_SLOPE * x.z;
        x.w = x.w > 0.f ? x.w : LEAKY_SLOPE * x.w;
        __builtin_nontemporal_store(
            x, reinterpret_cast<f32x4*>(out + (long long)gr * GCN_D + cq * 4));
    }
}

// ---------------- R3 fallback: chains + f32 gather ----------------

__global__ void build_nodes_kernel(const int* __restrict__ row,
                                   const int* __restrict__ col,
                                   const float* __restrict__ val,
                                   int E,
                                   int* __restrict__ head,
                                   int4* __restrict__ node) {
    int stride = gridDim.x * blockDim.x;
    for (int i = blockIdx.x * blockDim.x + threadIdx.x; i < E; i += stride) {
        int   r = row[i];
        int   c = col[i];
        float v = val[i];
        int prev = atomicExch(&head[r * NCHAIN_FB + (i & (NCHAIN_FB - 1))], i);
        node[i] = make_int4(prev, c, __float_as_int(v), 0);
    }
}

__global__ void __launch_bounds__(256)
reduce_nodes_kernel(const int* __restrict__ head,
                    const int4* __restrict__ node,
                    const float* __restrict__ embeds,
                    float* __restrict__ out,
                    int N) {
    int wave = (int)((blockIdx.x * (long long)blockDim.x + threadIdx.x) >> 6);
    int lane = threadIdx.x & 63;
    if (wave >= N) return;

    const float2* eb = reinterpret_cast<const float2*>(embeds);
    int4 h = reinterpret_cast<const int4*>(head)[wave];
    int e0 = h.x, e1 = h.y, e2 = h.z, e3 = h.w;

    float ax = 0.f, ay = 0.f;

    while ((e0 & e1 & e2 & e3) != -1) {
        int i0 = e0 >= 0 ? e0 : 0;
        int i1 = e1 >= 0 ? e1 : 0;
        int i2 = e2 >= 0 ? e2 : 0;
        int i3 = e3 >= 0 ? e3 : 0;

        int4 n0 = node[i0];
        int4 n1 = node[i1];
        int4 n2 = node[i2];
        int4 n3 = node[i3];

        int c0 = e0 >= 0 ? n0.y : 0;
        int c1 = e1 >= 0 ? n1.y : 0;
        int c2 = e2 >= 0 ? n2.y : 0;
        int c3 = e3 >= 0 ? n3.y : 0;

        float2 m0 = eb[(long long)c0 * 64 + lane];
        float2 m1 = eb[(long long)c1 * 64 + lane];
        float2 m2 = eb[(long long)c2 * 64 + lane];
        float2 m3 = eb[(long long)c3 * 64 + lane];

        float v0 = e0 >= 0 ? __int_as_float(n0.z) : 0.f;
        float v1 = e1 >= 0 ? __int_as_float(n1.z) : 0.f;
        float v2 = e2 >= 0 ? __int_as_float(n2.z) : 0.f;
        float v3 = e3 >= 0 ? __int_as_float(n3.z) : 0.f;

        ax += v0 * m0.x; ay += v0 * m0.y;
        ax += v1 * m1.x; ay += v1 * m1.y;
        ax += v2 * m2.x; ay += v2 * m2.y;
        ax += v3 * m3.x; ay += v3 * m3.y;

        e0 = e0 >= 0 ? n0.x : -1;
        e1 = e1 >= 0 ? n1.x : -1;
        e2 = e2 >= 0 ? n2.x : -1;
        e3 = e3 >= 0 ? n3.x : -1;
    }

    ax = ax > 0.f ? ax : LEAKY_SLOPE * ax;
    ay = ay > 0.f ? ay : LEAKY_SLOPE * ay;
    reinterpret_cast<float2*>(out)[(long long)wave * 64 + lane] =
        make_float2(ax, ay);
}

// ---------------- R0 fallback: atomic scatter ----------------

__global__ void gcn_scatter_kernel(const int* __restrict__ row_idx,
                                   const int* __restrict__ col_idx,
                                   const float* __restrict__ vals,
                                   const float* __restrict__ embeds,
                                   float* __restrict__ out,
                                   int E) {
    long long tid = (long long)blockIdx.x * blockDim.x + threadIdx.x;
    long long e = tid >> 5;
    if (e >= E) return;
    int q = (int)(tid & 31);
    int row = row_idx[e];
    int col = col_idx[e];
    float v = vals[e];
    const float4* src =
        reinterpret_cast<const float4*>(embeds + (long long)col * GCN_D) + q;
    float4 m = *src;
    float* dst = out + (long long)row * GCN_D + (long long)q * 4;
    atomicAdd(dst + 0, v * m.x);
    atomicAdd(dst + 1, v * m.y);
    atomicAdd(dst + 2, v * m.z);
    atomicAdd(dst + 3, v * m.w);
}

__global__ void gcn_leaky_relu_kernel(float* __restrict__ out, int n4) {
    int i = blockIdx.x * blockDim.x + threadIdx.x;
    if (i >= n4) return;
    float4* p = reinterpret_cast<float4*>(out) + i;
    float4 x = *p;
    x.x = x.x > 0.f ? x.x : LEAKY_SLOPE * x.x;
    x.y = x.y > 0.f ? x.y : LEAKY_SLOPE * x.y;
    x.z = x.z > 0.f ? x.z : LEAKY_SLOPE * x.z;
    x.w = x.w > 0.f ? x.w : LEAKY_SLOPE * x.w;
    *p = x;
}

// ---------------------------------------------------------------------------

extern "C" void kernel_launch(void* const* d_in, const int* in_sizes, int n_in,
                              void* d_out, int out_size, void* d_ws, size_t ws_size,
                              hipStream_t stream) {
    const int*   edge_index = (const int*)d_in[0];   // (2, E) flat, int32
    const float* edge_vals  = (const float*)d_in[1]; // (E,)
    const float* embeds     = (const float*)d_in[2]; // (N, 128) f32
    float*       out        = (float*)d_out;         // (N, 128) f32

    const int E = in_sizes[1];
    const int N = out_size / GCN_D;                  // 100000
    const int* row = edge_index;
    const int* col = edge_index + E;

    const int block = 256;
    const int nbins = (N + RPB - 1) / RPB;           // 782
    const int M     = nbins * NBLK;                  // 200192
    const int CH    = (E + NBLK - 1) / NBLK;         // 12500

    // R6 ws layout: hist/scan[M u32] | entry[E uint2] | half-embeds[N*128 f16]
    size_t hist_b = (((size_t)M * sizeof(unsigned)) + 255) & ~(size_t)255;
    size_t ent_b  = (((size_t)E * sizeof(uint2)) + 255) & ~(size_t)255;
    size_t half_b = (size_t)N * GCN_D * sizeof(__half);
    size_t need_r6 = hist_b + ent_b + half_b;        // ~52 MB

    size_t head_fb = (size_t)N * NCHAIN_FB * sizeof(int);
    size_t need_r3 = head_fb + (size_t)E * sizeof(int4);

    if (ws_size >= need_r6 && nbins <= NBINS_MAX) {
        unsigned* hist  = (unsigned*)d_ws;
        uint2*    entry = reinterpret_cast<uint2*>((char*)d_ws + hist_b);
        u32x4*    h8    = reinterpret_cast<u32x4*>((char*)d_ws + hist_b + ent_b);

        int n8 = N * (GCN_D / 8);                    // 1.6M groups of 8 floats
        int convBlocks = (n8 + block - 1) / block;   // 6250

        hist_convert_kernel<<<NBLK + convBlocks, block, 0, stream>>>(
            row, E, CH, nbins, hist,
            reinterpret_cast<const f32x4*>(embeds), n8, h8);

        scan_kernel<<<1, 1024, 0, stream>>>(hist, M);

        scatter_kernel<<<NBLK, block, 0, stream>>>(
            row, col, edge_vals, E, CH, nbins, hist, entry);

        bin_reduce_kernel<<<nbins, 512, 0, stream>>>(
            hist, entry, reinterpret_cast<const __half2*>(h8), out, E, N, nbins);
    } else if (ws_size >= need_r3) {
        int*  head = (int*)d_ws;
        int4* node = reinterpret_cast<int4*>((char*)d_ws + head_fb);

        hipMemsetAsync(head, 0xFF, head_fb, stream);
        build_nodes_kernel<<<2048, block, 0, stream>>>(row, col, edge_vals,
                                                       E, head, node);

        long long threads = (long long)N * 64;
        int rblocks = (int)((threads + block - 1) / block);
        reduce_nodes_kernel<<<rblocks, block, 0, stream>>>(
            head, node, embeds, out, N);
    } else {
        hipMemsetAsync(d_out, 0, (size_t)out_size * sizeof(float), stream);
        long long total_threads = (long long)E * 32;
        long long grid = (total_threads + block - 1) / block;
        gcn_scatter_kernel<<<(unsigned)grid, block, 0, stream>>>(
            row, col, edge_vals, embeds, out, E);
        int n4 = out_size / 4;
        gcn_leaky_relu_kernel<<<(n4 + 255) / 256, 256, 0, stream>>>(out, n4);
    }
}

// Round 5
// 202.585 us; speedup vs baseline: 15.2160x; 15.2160x over previous
//
#include <hip/hip_runtime.h>
#include <hip/hip_fp16.h>

// GCN layer: out = leaky_relu( segment_sum(edge_vals[:,None] * embeds[col], row, N), 0.5 )
// E = 3.2M, N = 100000, D = 128, f32 in/out.
//
// R7: R6's bin_reduce used atomicAdd(float) on LDS -> HIP emits a CAS retry
//     loop (no native fp atomics without unsafe-fp-atomics) -> 2.7ms crater.
//     Replace with a fully FP-atomic-free reduce:
//       - counting-sort the bin's entries BY ROW in LDS (u32 atomics only,
//         native ds_add_rtn_u32),
//       - each wave owns 8 rows, accumulates its rows' contiguous entries in
//         REGISTERS with an 8-deep gather unroll, stores directly.
//     Bins = 64 rows (1563 bins), CAP=3072 entries (24KB LDS) -> 4 blocks/CU,
//     32 waves/CU x 8 outstanding gathers = ~256 in flight (R4 had ~40).
//     Single-block scan -> 3-pass multi-block scan. fp16 table stores are
//     cache-allocated (no nt) so gathers hit L2/L3.
// Pipeline: hist(+fused f32->f16 convert) -> scanA/B/C -> scatter -> bin_reduce.
// No global atomics anywhere in the fast path.

#define GCN_D       128
#define LEAKY_SLOPE 0.5f
#define NBLK        256      // hist/scatter blocks (chunk partition of E)
#define RPB         64       // rows per bin
#define RPB_SH      6
#define CAP         3072     // sorted entries per LDS chunk (24 KB)
#define NBINS_MAX   2048
#define SCAN_G      512      // scan pass-A/C blocks
#define NCHAIN_FB   4

typedef float    f32x2 __attribute__((ext_vector_type(2)));
typedef float    f32x4 __attribute__((ext_vector_type(4)));
typedef unsigned u32x2 __attribute__((ext_vector_type(2)));
typedef unsigned u32x4 __attribute__((ext_vector_type(4)));

__device__ inline unsigned pack_half2(float a, float b) {
    __half2 h = __floats2half2_rn(a, b);
    return *reinterpret_cast<unsigned*>(&h);
}

// ---------------- Pass 1: histogram + fused f32->f16 conversion ----------------

__global__ void hist_convert_kernel(const int* __restrict__ row,
                                    int E, int CH, int nbins,
                                    unsigned* __restrict__ hist,   // [nbins][NBLK]
                                    const f32x4* __restrict__ emb4,
                                    int n8,
                                    u32x4* __restrict__ h8) {
    __shared__ unsigned h[NBINS_MAX];
    if ((int)blockIdx.x < NBLK) {
        int b = blockIdx.x;
        for (int i = threadIdx.x; i < nbins; i += blockDim.x) h[i] = 0u;
        __syncthreads();
        int s = b * CH;
        int e = min(E, s + CH);
        for (int i = s + threadIdx.x; i < e; i += blockDim.x)
            atomicAdd(&h[row[i] >> RPB_SH], 1u);
        __syncthreads();
        for (int i = threadIdx.x; i < nbins; i += blockDim.x)
            hist[(long long)i * NBLK + b] = h[i];
    } else {
        int bid = (int)blockIdx.x - NBLK;
        int nb  = (int)gridDim.x - NBLK;
        int stride = nb * blockDim.x;
        for (int i = bid * blockDim.x + threadIdx.x; i < n8; i += stride) {
            f32x4 a  = __builtin_nontemporal_load(&emb4[2 * i]);
            f32x4 b2 = __builtin_nontemporal_load(&emb4[2 * i + 1]);
            u32x4 o;
            o.x = pack_half2(a.x, a.y);
            o.y = pack_half2(a.z, a.w);
            o.z = pack_half2(b2.x, b2.y);
            o.w = pack_half2(b2.z, b2.w);
            h8[i] = o;   // cache-allocate: gathers want this resident
        }
    }
}

// ---------------- Pass 2: 3-pass multi-block exclusive scan ----------------

__global__ void __launch_bounds__(256)
scanA_kernel(const unsigned* __restrict__ data, int M, int chunk,
             unsigned* __restrict__ bsum) {
    __shared__ unsigned red[256];
    int b = blockIdx.x, t = threadIdx.x;
    long long s = (long long)b * chunk;
    unsigned acc = 0;
    for (int i = t; i < chunk; i += 256) {
        long long j = s + i;
        if (j < M) acc += data[j];
    }
    red[t] = acc;
    __syncthreads();
    for (int off = 128; off > 0; off >>= 1) {
        if (t < off) red[t] += red[t + off];
        __syncthreads();
    }
    if (t == 0) bsum[b] = red[0];
}

__global__ void __launch_bounds__(512)
scanB_kernel(unsigned* __restrict__ bsum, int G) {
    __shared__ unsigned s[512];
    int t = threadIdx.x;
    unsigned v = (t < G) ? bsum[t] : 0u;
    s[t] = v;
    __syncthreads();
    for (int off = 1; off < 512; off <<= 1) {
        unsigned u = (t >= off) ? s[t - off] : 0u;
        __syncthreads();
        s[t] += u;
        __syncthreads();
    }
    if (t < G) bsum[t] = (t == 0) ? 0u : s[t - 1];
}

__global__ void __launch_bounds__(256)
scanC_kernel(unsigned* __restrict__ data, int M, int chunk,
             const unsigned* __restrict__ bsum) {
    __shared__ unsigned pre[256];
    int b = blockIdx.x, t = threadIdx.x;
    long long s0 = (long long)b * chunk;
    long long s1 = s0 + chunk;
    int ept = (chunk + 255) / 256;
    long long ts = s0 + (long long)t * ept;

    unsigned acc = 0;
    for (int i = 0; i < ept; ++i) {
        long long j = ts + i;
        if (j < s1 && j < M) acc += data[j];
    }
    pre[t] = acc;
    __syncthreads();
    for (int off = 1; off < 256; off <<= 1) {
        unsigned u = (t >= off) ? pre[t - off] : 0u;
        __syncthreads();
        pre[t] += u;
        __syncthreads();
    }
    unsigned run = bsum[b] + ((t == 0) ? 0u : pre[t - 1]);
    for (int i = 0; i < ept; ++i) {
        long long j = ts + i;
        if (j < s1 && j < M) {
            unsigned v = data[j];
            data[j] = run;
            run += v;
        }
    }
}

// ---------------- Pass 3: scatter entries at deterministic offsets ----------------

__global__ void scatter_kernel(const int* __restrict__ row,
                               const int* __restrict__ col,
                               const float* __restrict__ val,
                               int E, int CH, int nbins,
                               const unsigned* __restrict__ scanned, // [nbins][NBLK]
                               u32x2* __restrict__ entry) {
    __shared__ unsigned cur[NBINS_MAX];
    int b = blockIdx.x;
    for (int i = threadIdx.x; i < nbins; i += blockDim.x)
        cur[i] = scanned[(long long)i * NBLK + b];
    __syncthreads();

    int s = b * CH;
    int e = min(E, s + CH);
    for (int i = s + threadIdx.x; i < e; i += blockDim.x) {
        int r = row[i];
        unsigned key = ((unsigned)(r & (RPB - 1)) << 17) | (unsigned)col[i];
        unsigned pos = atomicAdd(&cur[r >> RPB_SH], 1u);   // native u32 LDS atomic
        u32x2 q; q.x = key; q.y = __float_as_uint(val[i]);
        entry[pos] = q;
    }
}

// ---------------- Pass 4: per-bin LDS counting sort + register reduce ----------------

__global__ void __launch_bounds__(512)
bin_reduce_kernel(const unsigned* __restrict__ scanned,
                  const u32x2* __restrict__ entry,
                  const __half2* __restrict__ ebh,   // N*64 half2
                  float* __restrict__ out,
                  int E, int N, int nbins) {
    __shared__ u32x2    sorted[CAP];         // 24 KB
    __shared__ unsigned cnt[RPB];
    __shared__ unsigned offs[RPB];
    __shared__ unsigned cur[RPB];

    int b    = blockIdx.x;
    int tid  = threadIdx.x;
    int wave = tid >> 6;     // 0..7
    int lane = tid & 63;

    int seg0 = (int)scanned[(long long)b * NBLK];
    int seg1 = (b + 1 < nbins) ? (int)scanned[(long long)(b + 1) * NBLK] : E;

    float ax[8], ay[8];
    #pragma unroll
    for (int j = 0; j < 8; ++j) { ax[j] = 0.f; ay[j] = 0.f; }

    for (int cs = seg0; cs < seg1; cs += CAP) {
        int n = min(CAP, seg1 - cs);

        if (tid < RPB) cnt[tid] = 0u;
        __syncthreads();

        // count (coalesced global read; u32 LDS atomics are native)
        for (int i = tid; i < n; i += 512) {
            u32x2 q = __builtin_nontemporal_load(&entry[cs + i]);
            atomicAdd(&cnt[q.x >> 17], 1u);
        }
        __syncthreads();

        if (tid == 0) {
            unsigned run = 0;
            for (int r = 0; r < RPB; ++r) {
                offs[r] = run; cur[r] = run; run += cnt[r];
            }
        }
        __syncthreads();

        // place into row-sorted LDS order (second read is L1/L2-hot)
        for (int i = tid; i < n; i += 512) {
            u32x2 q = __builtin_nontemporal_load(&entry[cs + i]);
            unsigned pos = atomicAdd(&cur[q.x >> 17], 1u);
            sorted[pos] = q;
        }
        __syncthreads();

        // each wave accumulates its 8 rows' contiguous entries in registers
        #pragma unroll
        for (int j = 0; j < 8; ++j) {
            int r  = (wave << 3) + j;
            int s  = (int)offs[r];
            int en = s + (int)cnt[r];
            int i  = s;
            for (; i + 8 <= en; i += 8) {
                u32x2 q0 = sorted[i],     q1 = sorted[i + 1];
                u32x2 q2 = sorted[i + 2], q3 = sorted[i + 3];
                u32x2 q4 = sorted[i + 4], q5 = sorted[i + 5];
                u32x2 q6 = sorted[i + 6], q7 = sorted[i + 7];
                __half2 m0 = ebh[(long long)(q0.x & 0x1FFFFu) * 64 + lane];
                __half2 m1 = ebh[(long long)(q1.x & 0x1FFFFu) * 64 + lane];
                __half2 m2 = ebh[(long long)(q2.x & 0x1FFFFu) * 64 + lane];
                __half2 m3 = ebh[(long long)(q3.x & 0x1FFFFu) * 64 + lane];
                __half2 m4 = ebh[(long long)(q4.x & 0x1FFFFu) * 64 + lane];
                __half2 m5 = ebh[(long long)(q5.x & 0x1FFFFu) * 64 + lane];
                __half2 m6 = ebh[(long long)(q6.x & 0x1FFFFu) * 64 + lane];
                __half2 m7 = ebh[(long long)(q7.x & 0x1FFFFu) * 64 + lane];
                float2 f;
                f = __half22float2(m0);
                ax[j] += __uint_as_float(q0.y) * f.x; ay[j] += __uint_as_float(q0.y) * f.y;
                f = __half22float2(m1);
                ax[j] += __uint_as_float(q1.y) * f.x; ay[j] += __uint_as_float(q1.y) * f.y;
                f = __half22float2(m2);
                ax[j] += __uint_as_float(q2.y) * f.x; ay[j] += __uint_as_float(q2.y) * f.y;
                f = __half22float2(m3);
                ax[j] += __uint_as_float(q3.y) * f.x; ay[j] += __uint_as_float(q3.y) * f.y;
                f = __half22float2(m4);
                ax[j] += __uint_as_float(q4.y) * f.x; ay[j] += __uint_as_float(q4.y) * f.y;
                f = __half22float2(m5);
                ax[j] += __uint_as_float(q5.y) * f.x; ay[j] += __uint_as_float(q5.y) * f.y;
                f = __half22float2(m6);
                ax[j] += __uint_as_float(q6.y) * f.x; ay[j] += __uint_as_float(q6.y) * f.y;
                f = __half22float2(m7);
                ax[j] += __uint_as_float(q7.y) * f.x; ay[j] += __uint_as_float(q7.y) * f.y;
            }
            for (; i < en; ++i) {
                u32x2 q = sorted[i];
                __half2 mm = ebh[(long long)(q.x & 0x1FFFFu) * 64 + lane];
                float2 f = __half22float2(mm);
                ax[j] += __uint_as_float(q.y) * f.x;
                ay[j] += __uint_as_float(q.y) * f.y;
            }
        }
        __syncthreads();
    }

    // fused leaky_relu + coalesced 512B stores (bin owns rows exclusively)
    int gr0 = b * RPB + (wave << 3);
    #pragma unroll
    for (int j = 0; j < 8; ++j) {
        int gr = gr0 + j;
        if (gr < N) {
            float x = ax[j], y = ay[j];
            x = x > 0.f ? x : LEAKY_SLOPE * x;
            y = y > 0.f ? y : LEAKY_SLOPE * y;
            f32x2 o; o.x = x; o.y = y;
            __builtin_nontemporal_store(
                o, reinterpret_cast<f32x2*>(out) + (long long)gr * 64 + lane);
        }
    }
}

// ---------------- R3 fallback: chains + f32 gather ----------------

__global__ void build_nodes_kernel(const int* __restrict__ row,
                                   const int* __restrict__ col,
                                   const float* __restrict__ val,
                                   int E,
                                   int* __restrict__ head,
                                   int4* __restrict__ node) {
    int stride = gridDim.x * blockDim.x;
    for (int i = blockIdx.x * blockDim.x + threadIdx.x; i < E; i += stride) {
        int   r = row[i];
        int   c = col[i];
        float v = val[i];
        int prev = atomicExch(&head[r * NCHAIN_FB + (i & (NCHAIN_FB - 1))], i);
        node[i] = make_int4(prev, c, __float_as_int(v), 0);
    }
}

__global__ void __launch_bounds__(256)
reduce_nodes_kernel(const int* __restrict__ head,
                    const int4* __restrict__ node,
                    const float* __restrict__ embeds,
                    float* __restrict__ out,
                    int N) {
    int wave = (int)((blockIdx.x * (long long)blockDim.x + threadIdx.x) >> 6);
    int lane = threadIdx.x & 63;
    if (wave >= N) return;

    const float2* eb = reinterpret_cast<const float2*>(embeds);
    int4 h = reinterpret_cast<const int4*>(head)[wave];
    int e0 = h.x, e1 = h.y, e2 = h.z, e3 = h.w;

    float ax = 0.f, ay = 0.f;

    while ((e0 & e1 & e2 & e3) != -1) {
        int i0 = e0 >= 0 ? e0 : 0;
        int i1 = e1 >= 0 ? e1 : 0;
        int i2 = e2 >= 0 ? e2 : 0;
        int i3 = e3 >= 0 ? e3 : 0;

        int4 n0 = node[i0];
        int4 n1 = node[i1];
        int4 n2 = node[i2];
        int4 n3 = node[i3];

        int c0 = e0 >= 0 ? n0.y : 0;
        int c1 = e1 >= 0 ? n1.y : 0;
        int c2 = e2 >= 0 ? n2.y : 0;
        int c3 = e3 >= 0 ? n3.y : 0;

        float2 m0 = eb[(long long)c0 * 64 + lane];
        float2 m1 = eb[(long long)c1 * 64 + lane];
        float2 m2 = eb[(long long)c2 * 64 + lane];
        float2 m3 = eb[(long long)c3 * 64 + lane];

        float v0 = e0 >= 0 ? __int_as_float(n0.z) : 0.f;
        float v1 = e1 >= 0 ? __int_as_float(n1.z) : 0.f;
        float v2 = e2 >= 0 ? __int_as_float(n2.z) : 0.f;
        float v3 = e3 >= 0 ? __int_as_float(n3.z) : 0.f;

        ax += v0 * m0.x; ay += v0 * m0.y;
        ax += v1 * m1.x; ay += v1 * m1.y;
        ax += v2 * m2.x; ay += v2 * m2.y;
        ax += v3 * m3.x; ay += v3 * m3.y;

        e0 = e0 >= 0 ? n0.x : -1;
        e1 = e1 >= 0 ? n1.x : -1;
        e2 = e2 >= 0 ? n2.x : -1;
        e3 = e3 >= 0 ? n3.x : -1;
    }

    ax = ax > 0.f ? ax : LEAKY_SLOPE * ax;
    ay = ay > 0.f ? ay : LEAKY_SLOPE * ay;
    reinterpret_cast<float2*>(out)[(long long)wave * 64 + lane] =
        make_float2(ax, ay);
}

// ---------------- R0 fallback: atomic scatter ----------------

__global__ void gcn_scatter_kernel(const int* __restrict__ row_idx,
                                   const int* __restrict__ col_idx,
                                   const float* __restrict__ vals,
                                   const float* __restrict__ embeds,
                                   float* __restrict__ out,
                                   int E) {
    long long tid = (long long)blockIdx.x * blockDim.x + threadIdx.x;
    long long e = tid >> 5;
    if (e >= E) return;
    int q = (int)(tid & 31);
    int row = row_idx[e];
    int col = col_idx[e];
    float v = vals[e];
    const float4* src =
        reinterpret_cast<const float4*>(embeds + (long long)col * GCN_D) + q;
    float4 m = *src;
    float* dst = out + (long long)row * GCN_D + (long long)q * 4;
    atomicAdd(dst + 0, v * m.x);
    atomicAdd(dst + 1, v * m.y);
    atomicAdd(dst + 2, v * m.z);
    atomicAdd(dst + 3, v * m.w);
}

__global__ void gcn_leaky_relu_kernel(float* __restrict__ out, int n4) {
    int i = blockIdx.x * blockDim.x + threadIdx.x;
    if (i >= n4) return;
    float4* p = reinterpret_cast<float4*>(out) + i;
    float4 x = *p;
    x.x = x.x > 0.f ? x.x : LEAKY_SLOPE * x.x;
    x.y = x.y > 0.f ? x.y : LEAKY_SLOPE * x.y;
    x.z = x.z > 0.f ? x.z : LEAKY_SLOPE * x.z;
    x.w = x.w > 0.f ? x.w : LEAKY_SLOPE * x.w;
    *p = x;
}

// ---------------------------------------------------------------------------

extern "C" void kernel_launch(void* const* d_in, const int* in_sizes, int n_in,
                              void* d_out, int out_size, void* d_ws, size_t ws_size,
                              hipStream_t stream) {
    const int*   edge_index = (const int*)d_in[0];   // (2, E) flat, int32
    const float* edge_vals  = (const float*)d_in[1]; // (E,)
    const float* embeds     = (const float*)d_in[2]; // (N, 128) f32
    float*       out        = (float*)d_out;         // (N, 128) f32

    const int E = in_sizes[1];
    const int N = out_size / GCN_D;                  // 100000
    const int* row = edge_index;
    const int* col = edge_index + E;

    const int block = 256;
    const int nbins = (N + RPB - 1) / RPB;           // 1563
    const int M     = nbins * NBLK;                  // 400128
    const int CH    = (E + NBLK - 1) / NBLK;         // 12500
    const int chunk = (M + SCAN_G - 1) / SCAN_G;     // 782

    // R7 ws layout: hist[M u32] | bsum[SCAN_G u32] | entry[E u32x2] | fp16 table
    size_t hist_b = (((size_t)M * sizeof(unsigned)) + 255) & ~(size_t)255;
    size_t bsum_b = (((size_t)SCAN_G * sizeof(unsigned)) + 255) & ~(size_t)255;
    size_t ent_b  = (((size_t)E * sizeof(u32x2)) + 255) & ~(size_t)255;
    size_t half_b = (size_t)N * GCN_D * sizeof(__half);
    size_t need_r7 = hist_b + bsum_b + ent_b + half_b;   // ~53 MB

    size_t head_fb = (size_t)N * NCHAIN_FB * sizeof(int);
    size_t need_r3 = head_fb + (size_t)E * sizeof(int4);

    if (ws_size >= need_r7 && nbins <= NBINS_MAX) {
        unsigned* hist  = (unsigned*)d_ws;
        unsigned* bsum  = reinterpret_cast<unsigned*>((char*)d_ws + hist_b);
        u32x2*    entry = reinterpret_cast<u32x2*>((char*)d_ws + hist_b + bsum_b);
        u32x4*    h8    = reinterpret_cast<u32x4*>((char*)d_ws + hist_b + bsum_b + ent_b);

        int n8 = N * (GCN_D / 8);                    // 1.6M groups of 8 floats
        int convBlocks = (n8 + block - 1) / block;   // 6250

        hist_convert_kernel<<<NBLK + convBlocks, block, 0, stream>>>(
            row, E, CH, nbins, hist,
            reinterpret_cast<const f32x4*>(embeds), n8, h8);

        scanA_kernel<<<SCAN_G, 256, 0, stream>>>(hist, M, chunk, bsum);
        scanB_kernel<<<1, 512, 0, stream>>>(bsum, SCAN_G);
        scanC_kernel<<<SCAN_G, 256, 0, stream>>>(hist, M, chunk, bsum);

        scatter_kernel<<<NBLK, block, 0, stream>>>(
            row, col, edge_vals, E, CH, nbins, hist, entry);

        bin_reduce_kernel<<<nbins, 512, 0, stream>>>(
            hist, entry, reinterpret_cast<const __half2*>(h8), out, E, N, nbins);
    } else if (ws_size >= need_r3) {
        int*  head = (int*)d_ws;
        int4* node = reinterpret_cast<int4*>((char*)d_ws + head_fb);

        hipMemsetAsync(head, 0xFF, head_fb, stream);
        build_nodes_kernel<<<2048, block, 0, stream>>>(row, col, edge_vals,
                                                       E, head, node);

        long long threads = (long long)N * 64;
        int rblocks = (int)((threads + block - 1) / block);
        reduce_nodes_kernel<<<rblocks, block, 0, stream>>>(
            head, node, embeds, out, N);
    } else {
        hipMemsetAsync(d_out, 0, (size_t)out_size * sizeof(float), stream);
        long long total_threads = (long long)E * 32;
        long long grid = (total_threads + block - 1) / block;
        gcn_scatter_kernel<<<(unsigned)grid, block, 0, stream>>>(
            row, col, edge_vals, embeds, out, E);
        int n4 = out_size / 4;
        gcn_leaky_relu_kernel<<<(n4 + 255) / 256, 256, 0, stream>>>(out, n4);
    }
}